// Round 12
// baseline (192.916 us; speedup 1.0000x reference)
//
#include <hip/hip_runtime.h>

// out[b,f,t] = sum_{c,dt} exp(-g*x[b,c,t+dt])[x!=0] * w[c*48+dt*16+f]
// G-shift formulation: G_dt = E(t x c) * W_dt(c x f)  (NO t-shift in GEMM),
// out[t,f] = sum_dt G_dt[t+dt,f] applied in the fp32 epilogue.
// => A-fragment (8-gather of E) is SHARED by the 3 dt-MFMAs: 32 gathers/wave
//    instead of 88; DS-pipe ~18us chip-wide, well under the 41us HBM floor.
// E pitch 51 words: gather banks {0,8,16,24}+tcol/2 = all 32, conflict-free.
// WL pitch 36 words: B-frag b128 reads uniform 8 words/bank (optimal).
#define BB     64
#define NNCH   10000
#define TOUT   98
#define FF     16
#define CPB    64
#define NCHUNK 157            // ceil(10000/64); grid = 64*157
#define EPITCH 102            // E row pitch in ushorts (51 dwords)
#define WLP    72             // WL row pitch in ushorts (36 dwords)
#define ACCN   (TOUT * FF)    // 1568

typedef __attribute__((ext_vector_type(8))) short s8v;   // 8 bf16
typedef __attribute__((ext_vector_type(4))) float f4v;   // 4 fp32 acc

__device__ __forceinline__ ushort bf_rne(float v) {
    unsigned b = __float_as_uint(v);
    return (ushort)((b + 0x7FFFu + ((b >> 16) & 1u)) >> 16);
}

__global__ __launch_bounds__(256) void tgcnn_gemm(
    const float* __restrict__ x,      // (B, NN, T=100) fp32
    const float* __restrict__ w,      // (NN*3, 16) fp32: c*48 + dt*16 + f
    const float* __restrict__ gammat, // fp32 scalar
    float* __restrict__ ws)           // (B, TOUT, F) fp32, pre-zeroed
{
    // E[c][t]: 64 rows x 102 ushorts (+16 pad: tau<=111 overreads are finite
    // and feed only masked D-rows m>=98).  WL[dt][f][c]: B operand.
    __shared__ __align__(16) ushort E[CPB * EPITCH + 16];
    __shared__ __align__(16) ushort WL[3][FF][WLP];

    const int tid = threadIdx.x;
    const int bid = blockIdx.x;
    const int b   = bid / NCHUNK;
    const int cs  = bid - b * NCHUNK;
    const int cbase = cs * CPB;

    const float gt    = gammat[0];
    const float gamma = 10.0f / (1.0f + __expf(-gt));
    const float kk    = -gamma * 1.4426950408889634f;   // exp(-g*x)=exp2(kk*x)

    // ---- stage E: coalesced float4 (4 t of one c) -> exp -> 2x b32 ----
    const float4* x4 = (const float4*)x;
    unsigned* e32 = (unsigned*)E;
    #pragma unroll
    for (int rr = 0; rr < 7; ++rr) {
        const int i = rr * 256 + tid;
        if (i < CPB * 25) {
            const int cl = i / 25, q = i - cl * 25;
            const int c  = cbase + cl;
            float4 v = make_float4(0.f, 0.f, 0.f, 0.f);
            if (c < NNCH) v = x4[((size_t)b * NNCH + c) * 25 + q];
            const unsigned e0 = (v.x != 0.f) ? bf_rne(exp2f(kk * v.x)) : 0;
            const unsigned e1 = (v.y != 0.f) ? bf_rne(exp2f(kk * v.y)) : 0;
            const unsigned e2 = (v.z != 0.f) ? bf_rne(exp2f(kk * v.z)) : 0;
            const unsigned e3 = (v.w != 0.f) ? bf_rne(exp2f(kk * v.w)) : 0;
            const int wd = cl * 51 + 2 * q;       // dword index, 4B-aligned
            e32[wd]     = e0 | (e1 << 16);
            e32[wd + 1] = e2 | (e3 << 16);
        }
    }

    // ---- stage W: w[c*48+dt*16+f] -> WL[dt][f][c], zero-filled tail ----
    const float4* wg4 = (const float4*)w;
    #pragma unroll
    for (int rr = 0; rr < 3; ++rr) {
        const int i  = rr * 256 + tid;
        const int cl = i / 12, r = i - cl * 12;
        const int c  = cbase + cl;
        float4 wv = make_float4(0.f, 0.f, 0.f, 0.f);
        if (c < NNCH) wv = wg4[(size_t)c * 12 + r];
        const int dt = r >> 2, f0 = (r & 3) * 4;
        WL[dt][f0 + 0][cl] = bf_rne(wv.x);
        WL[dt][f0 + 1][cl] = bf_rne(wv.y);
        WL[dt][f0 + 2][cl] = bf_rne(wv.z);
        WL[dt][f0 + 3][cl] = bf_rne(wv.w);
    }
    __syncthreads();   // the only barrier

    // ---- MFMA: 7 t-tiles; wave owns {wave, wave+4} (wave 3: tile 3 only)
    const int wave = tid >> 6, lane = tid & 63;
    const int tcol = lane & 15;        // A row (t in tile) / B,D col (f)
    const int kb   = lane >> 4;        // k-octet
    const int tile0 = wave, tile1 = wave + 4;
    const bool two  = (tile1 < 7);
    const int tau0 = tile0 * 16 + tcol;
    const int tau1 = tile1 * 16 + tcol;

    f4v acc0[3] = {{0.f,0.f,0.f,0.f},{0.f,0.f,0.f,0.f},{0.f,0.f,0.f,0.f}};
    f4v acc1[3] = {{0.f,0.f,0.f,0.f},{0.f,0.f,0.f,0.f},{0.f,0.f,0.f,0.f}};

    #pragma unroll
    for (int ks = 0; ks < 2; ++ks) {
        const int cb = ks * 32 + kb * 8;

        // A-fragments: 8-gather each, conflict-free (pitch 51 dwords).
        // SHARED across the 3 dt-MFMAs below.
        s8v a0, a1;
        #pragma unroll
        for (int j = 0; j < 8; ++j) a0[j] = (short)E[(cb + j) * EPITCH + tau0];
        if (two) {
            #pragma unroll
            for (int j = 0; j < 8; ++j) a1[j] = (short)E[(cb + j) * EPITCH + tau1];
        }

        #pragma unroll
        for (int dt = 0; dt < 3; ++dt) {
            const s8v bf = *(const s8v*)&WL[dt][tcol][cb];   // one b128
            acc0[dt] = __builtin_amdgcn_mfma_f32_16x16x32_bf16(a0, bf, acc0[dt], 0, 0, 0);
            if (two)
                acc1[dt] = __builtin_amdgcn_mfma_f32_16x16x32_bf16(a1, bf, acc1[dt], 0, 0, 0);
        }
    }

    // ---- epilogue: out[t] += G_dt[t+dt]  =>  t = m - dt; atomics to d_ws
    // (L2-cheap, proven r3/r9). D: col=lane&15 (=f), row=(lane>>4)*4+r (=m).
    float* wsb = ws + (size_t)b * ACCN;
    const int f = lane & 15;
    const int rbase = (lane >> 4) * 4;
    #pragma unroll
    for (int r = 0; r < 4; ++r) {
        const int m0 = tile0 * 16 + rbase + r;
        #pragma unroll
        for (int dt = 0; dt < 3; ++dt) {
            const int t = m0 - dt;
            if ((unsigned)t < (unsigned)TOUT)
                atomicAdd(&wsb[t * FF + f], acc0[dt][r]);
        }
    }
    if (two) {
        #pragma unroll
        for (int r = 0; r < 4; ++r) {
            const int m1 = tile1 * 16 + rbase + r;
            #pragma unroll
            for (int dt = 0; dt < 3; ++dt) {
                const int t = m1 - dt;
                if ((unsigned)t < (unsigned)TOUT)
                    atomicAdd(&wsb[t * FF + f], acc1[dt][r]);
            }
        }
    }
}

__global__ __launch_bounds__(256) void tgcnn_finalize(
    const float* __restrict__ ws, float* __restrict__ out)
{
    int i = blockIdx.x * 256 + threadIdx.x;
    if (i >= BB * FF * TOUT) return;
    int t = i % TOUT;
    int f = (i / TOUT) & (FF - 1);
    int b = i / (FF * TOUT);
    out[i] = ws[(size_t)b * ACCN + t * FF + f];   // (B,T,F) -> (B,F,1,T)
}

extern "C" void kernel_launch(void* const* d_in, const int* in_sizes, int n_in,
                              void* d_out, int out_size, void* d_ws, size_t ws_size,
                              hipStream_t stream) {
    const float* x = (const float*)d_in[0];
    const float* w = (const float*)d_in[1];
    const float* g = (const float*)d_in[2];
    float* ws = (float*)d_ws;

    hipMemsetAsync(d_ws, 0, (size_t)BB * ACCN * sizeof(float), stream);
    tgcnn_gemm<<<BB * NCHUNK, 256, 0, stream>>>(x, w, g, ws);
    tgcnn_finalize<<<(BB * FF * TOUT + 255) / 256, 256, 0, stream>>>(
        ws, (float*)d_out);
}

// Round 13
// 89.556 us; speedup vs baseline: 2.1541x; 2.1541x over previous
//
#include <hip/hip_runtime.h>

// out[b,f,t] = sum_{c,dt} exp(-g*x[b,c,t+dt])[x!=0] * w[c*48+dt*16+f]
// G-shift formulation: G_dt = E(t x c) * W_dt(c x f) with UNSHIFTED A, so the
// A-fragment (8-gather) is shared by the 3 dt-MFMAs (32 gathers + 6 b128 per
// wave per chunk vs r5's 88+12). dt-combine done IN LDS (plain stores into
// G planes aliasing dead E/WL, then gather G0[t]+G1[t+1]+G2[t+2]) and the
// result PLAIN-stored to an exclusive ws slice (r11: zero global atomics,
// which r12 proved cost ~3.5ns each at 47M).
#define BB     64
#define NNCH   10000
#define TOUT   98
#define FF     16
#define CPB    64
#define NCHUNK 157            // ceil(10000/64)
#define EPITCH 102            // E row pitch (ushort), 51 dwords
#define WLP    72             // WL row pitch (ushort)
#define GP     17             // G row pitch (float): breaks 16-word periodicity
#define GROWS  112
#define ACCN   (TOUT * FF)    // 1568
#define E_BYTES   ((CPB * EPITCH + 16) * 2)            // 13088
#define WL_BYTES  (3 * FF * WLP * 2)                   // 6912
#define G_BYTES   (3 * GROWS * GP * 4)                 // 22848
#define LDS_BYTES (G_BYTES)                            // > E+WL = 20000

typedef __attribute__((ext_vector_type(8))) short s8v;   // 8 bf16
typedef __attribute__((ext_vector_type(4))) float f4v;   // 4 fp32 acc

__device__ __forceinline__ ushort bf_rne(float v) {
    unsigned b = __float_as_uint(v);
    return (ushort)((b + 0x7FFFu + ((b >> 16) & 1u)) >> 16);
}

__global__ __launch_bounds__(256) void tgcnn_gemm(
    const float* __restrict__ x,      // (B, NN, T=100) fp32
    const float* __restrict__ w,      // (NN*3, 16) fp32: c*48 + dt*16 + f
    const float* __restrict__ gammat, // fp32 scalar
    float* __restrict__ ws,           // nco x (B, TOUT, F) fp32 excl. slices
    int nco, int ch)
{
    __shared__ __align__(16) char lds[LDS_BYTES];
    ushort* E  = (ushort*)lds;                         // E[c][t], pitch EPITCH
    unsigned* e32 = (unsigned*)lds;
    ushort (*WL)[FF][WLP] = (ushort(*)[FF][WLP])(lds + E_BYTES);
    float (*G)[GROWS][GP] = (float(*)[GROWS][GP])lds;  // aliases E/WL (dead)

    const int tid = threadIdx.x;
    const int bid = blockIdx.x;
    const int b   = bid / nco;
    const int co  = bid - b * nco;

    const float gt    = gammat[0];
    const float gamma = 10.0f / (1.0f + __expf(-gt));
    const float kk    = -gamma * 1.4426950408889634f;   // exp(-g*x)=exp2(kk*x)

    const int wave = tid >> 6, lane = tid & 63;
    const int tcol = lane & 15;        // A row (t in tile) / B,D col (f)
    const int kb   = lane >> 4;        // k-octet
    const int tile0 = wave, tile1 = wave + 4;
    const bool two  = (tile1 < 7);
    const int tau0 = tile0 * 16 + tcol;
    const int tau1 = tile1 * 16 + tcol;

    f4v acc0[3] = {{0.f,0.f,0.f,0.f},{0.f,0.f,0.f,0.f},{0.f,0.f,0.f,0.f}};
    f4v acc1[3] = {{0.f,0.f,0.f,0.f},{0.f,0.f,0.f,0.f},{0.f,0.f,0.f,0.f}};

    const float4* x4  = (const float4*)x;
    const float4* wg4 = (const float4*)w;

    for (int kc = 0; kc < ch; ++kc) {
        const int cs = co * ch + kc;
        if (cs >= NCHUNK) break;
        const int cbase = cs * CPB;

        if (kc) __syncthreads();

        // stage E: coalesced float4 (4 t of one c) -> exp -> 2x b32 writes
        for (int i = tid; i < CPB * 25; i += 256) {
            const int cl = i / 25, q = i - cl * 25;
            const int c  = cbase + cl;
            float4 v = make_float4(0.f, 0.f, 0.f, 0.f);
            if (c < NNCH) v = x4[((size_t)b * NNCH + c) * 25 + q];
            const unsigned e0 = (v.x != 0.f) ? bf_rne(exp2f(kk * v.x)) : 0;
            const unsigned e1 = (v.y != 0.f) ? bf_rne(exp2f(kk * v.y)) : 0;
            const unsigned e2 = (v.z != 0.f) ? bf_rne(exp2f(kk * v.z)) : 0;
            const unsigned e3 = (v.w != 0.f) ? bf_rne(exp2f(kk * v.w)) : 0;
            const int wd = cl * 51 + 2 * q;
            e32[wd]     = e0 | (e1 << 16);
            e32[wd + 1] = e2 | (e3 << 16);
        }

        // stage W: w[c*48+dt*16+f] -> WL[dt][f][c], zero-filled tail
        for (int i = tid; i < CPB * 12; i += 256) {
            const int cl = i / 12, r = i - cl * 12;
            const int c  = cbase + cl;
            float4 wv = make_float4(0.f, 0.f, 0.f, 0.f);
            if (c < NNCH) wv = wg4[(size_t)c * 12 + r];
            const int dt = r >> 2, f0 = (r & 3) * 4;
            WL[dt][f0 + 0][cl] = bf_rne(wv.x);
            WL[dt][f0 + 1][cl] = bf_rne(wv.y);
            WL[dt][f0 + 2][cl] = bf_rne(wv.z);
            WL[dt][f0 + 3][cl] = bf_rne(wv.w);
        }
        __syncthreads();

        // MFMA: A-fragment shared across the 3 dt-MFMAs
        #pragma unroll
        for (int ks = 0; ks < 2; ++ks) {
            const int cb = ks * 32 + kb * 8;

            s8v a0, a1;
            #pragma unroll
            for (int j = 0; j < 8; ++j) a0[j] = (short)E[(cb + j) * EPITCH + tau0];
            if (two) {
                #pragma unroll
                for (int j = 0; j < 8; ++j) a1[j] = (short)E[(cb + j) * EPITCH + tau1];
            }

            #pragma unroll
            for (int dt = 0; dt < 3; ++dt) {
                const s8v bf = *(const s8v*)&WL[dt][tcol][cb];
                acc0[dt] = __builtin_amdgcn_mfma_f32_16x16x32_bf16(a0, bf, acc0[dt], 0, 0, 0);
                if (two)
                    acc1[dt] = __builtin_amdgcn_mfma_f32_16x16x32_bf16(a1, bf, acc1[dt], 0, 0, 0);
            }
        }
    }

    // ---- in-LDS dt-combine ----
    __syncthreads();   // all MFMA reads of E/WL done; safe to alias as G
    {
        const int f = lane & 15;
        const int rbase = (lane >> 4) * 4;
        #pragma unroll
        for (int dt = 0; dt < 3; ++dt) {
            #pragma unroll
            for (int r = 0; r < 4; ++r) {
                G[dt][tile0 * 16 + rbase + r][f] = acc0[dt][r];
                if (two) G[dt][tile1 * 16 + rbase + r][f] = acc1[dt][r];
            }
        }
    }
    __syncthreads();

    // out[t,f] = G0[t] + G1[t+1] + G2[t+2]; plain store to exclusive slice
    float* wsb = ws + ((size_t)co * BB + b) * ACCN;
    for (int i = tid; i < ACCN; i += 256) {
        const int t = i >> 4, f = i & 15;
        wsb[i] = G[0][t][f] + G[1][t + 1][f] + G[2][t + 2][f];
    }
}

__global__ __launch_bounds__(256) void tgcnn_finalize(
    const float* __restrict__ ws, float* __restrict__ out, int nco)
{
    int i = blockIdx.x * 256 + threadIdx.x;
    if (i >= BB * FF * TOUT) return;
    int t = i % TOUT;
    int f = (i / TOUT) & (FF - 1);
    int b = i / (FF * TOUT);
    float s = 0.f;
    for (int co = 0; co < nco; ++co)
        s += ws[((size_t)co * BB + b) * ACCN + t * FF + f];
    out[i] = s;                        // (B,T,F) -> (B,F,1,T)
}

extern "C" void kernel_launch(void* const* d_in, const int* in_sizes, int n_in,
                              void* d_out, int out_size, void* d_ws, size_t ws_size,
                              hipStream_t stream) {
    const float* x = (const float*)d_in[0];
    const float* w = (const float*)d_in[1];
    const float* g = (const float*)d_in[2];
    float* ws = (float*)d_ws;

    const size_t slot = (size_t)BB * ACCN * sizeof(float);   // 401 KB
    int navail = (int)(ws_size / slot);
    int nco = navail < 1 ? 1 : (navail > 40 ? 40 : navail);
    int ch  = (NCHUNK + nco - 1) / nco;

    tgcnn_gemm<<<BB * nco, 256, 0, stream>>>(x, w, g, ws, nco, ch);
    tgcnn_finalize<<<(BB * FF * TOUT + 255) / 256, 256, 0, stream>>>(
        ws, (float*)d_out, nco);
}